// Round 5
// baseline (423.535 us; speedup 1.0000x reference)
//
#include <hip/hip_runtime.h>

typedef unsigned short u16;
typedef __attribute__((ext_vector_type(4))) unsigned short u16x4;
typedef __attribute__((ext_vector_type(8))) unsigned short u16x8;
typedef __attribute__((ext_vector_type(4))) unsigned int   u32x4;
typedef __attribute__((ext_vector_type(4))) float          f32x4;
typedef __attribute__((ext_vector_type(8))) __bf16         bf16x8;

#define MFMA16(a,b,c) __builtin_amdgcn_mfma_f32_16x16x32_bf16((a),(b),(c),0,0,0)
#define SCALE 0.125f

__device__ __forceinline__ u16 f2b(float f){
  unsigned u = __builtin_bit_cast(unsigned, f);
  u = (u + 0x7fffu + ((u >> 16) & 1u)) >> 16;
  return (u16)u;
}
__device__ __forceinline__ float b2f(u16 v){
  unsigned u = ((unsigned)v) << 16;
  return __builtin_bit_cast(float, u);
}
__device__ __forceinline__ void async16(const u16* g, u16* l){
  __builtin_amdgcn_global_load_lds(
      (const __attribute__((address_space(1))) unsigned*)g,
      (__attribute__((address_space(3))) unsigned*)l, 16, 0, 0);
}

// ---------------- cast f32 -> bf16 ----------------
__global__ void cast_k(const float* __restrict__ s, u16* __restrict__ d, int n4){
  int i = blockIdx.x * 256 + threadIdx.x;
  if (i < n4) {
    const float4 v = ((const float4*)s)[i];
    u16x4 o; o[0]=f2b(v.x); o[1]=f2b(v.y); o[2]=f2b(v.z); o[3]=f2b(v.w);
    ((u16x4*)d)[i] = o;
  }
}

// ---------------- GEMM: C[M,N] = A[M,K] @ B[N,K]^T (+bias), bf16 in, f32 acc ----
// OUT = u16 (bf16 store) or float (f32 store, for d_out chunks).
template <typename OUT>
__global__ __launch_bounds__(256, 2) void gemm_bt_k(
    const u16* __restrict__ A, const u16* __restrict__ Bm,
    const float* __restrict__ bias, OUT* __restrict__ Cb,
    int M, int N, int K)
{
  __shared__ u16 As[128*32];
  __shared__ u16 Bs[128*32];
  const int tid  = threadIdx.x;
  const int w    = tid >> 6, lane = tid & 63;
  const int quad = lane >> 4, l16 = lane & 15;
  const int wr   = w >> 1, wc = w & 1;
  const int m0 = blockIdx.x * 128, n0 = blockIdx.y * 128;

  f32x4 acc[4][4] = {};
  const int rowa = lane >> 2;        // 0..15
  const int ko   = (lane & 3) * 8;   // 0,8,16,24

  for (int k0 = 0; k0 < K; k0 += 32) {
    __syncthreads();
#pragma unroll
    for (int r = 0; r < 2; ++r) {
      int rb = (r*4 + w) * 16;
      async16(A  + (size_t)(m0 + rb + rowa)*K + k0 + ko, As + (r*4 + w)*512);
      async16(Bm + (size_t)(n0 + rb + rowa)*K + k0 + ko, Bs + (r*4 + w)*512);
    }
    __syncthreads();
    bf16x8 af[4], bfr[4];
#pragma unroll
    for (int i = 0; i < 4; ++i)
      af[i] = *(const bf16x8*)&As[(wr*64 + i*16 + l16)*32 + quad*8];
#pragma unroll
    for (int j = 0; j < 4; ++j)
      bfr[j] = *(const bf16x8*)&Bs[(wc*64 + j*16 + l16)*32 + quad*8];
#pragma unroll
    for (int i = 0; i < 4; ++i)
#pragma unroll
      for (int j = 0; j < 4; ++j)
        acc[i][j] = MFMA16(af[i], bfr[j], acc[i][j]);
  }
#pragma unroll
  for (int j = 0; j < 4; ++j) {
    int col = n0 + wc*64 + j*16 + l16;
    float bv = bias ? bias[col] : 0.0f;
#pragma unroll
    for (int i = 0; i < 4; ++i)
#pragma unroll
      for (int reg = 0; reg < 4; ++reg) {
        int row = m0 + wr*64 + i*16 + quad*4 + reg;
        float v = acc[i][j][reg] + bv;
        if constexpr (__is_same(OUT, float))
          Cb[(size_t)row*N + col] = v;
        else
          Cb[(size_t)row*N + col] = f2b(v);
      }
  }
}

// ---------------- fused flash attention: all 4 attentions in one launch ----------
// a=0: xc=attn(qy,kx,vx)  a=1: yc=attn(qx,ky,vy)  a=2: xt=attn(qtx,kx,vx)  a=3: yt=attn(qty,ky,vy)
__global__ __launch_bounds__(256, 2) void attn_k(
    const u16* __restrict__ qkv1, const u16* __restrict__ qkv2,
    u16* __restrict__ ao)
{
  const int qt = blockIdx.x;   // 0..15 q-tile
  const int bh = blockIdx.y;   // 0..31
  const int a  = blockIdx.z;   // 0..3
  const int b = bh >> 3, h = bh & 7;

  const u16* qsrc  = (a == 1 || a == 2) ? qkv1 : qkv2;
  const u16* kvsrc = (a & 1) ? qkv2 : qkv1;
  const int qoff = ((a >= 2) ? 1536 : 0) + h*64;
  const int koff = 512  + h*64;
  const int voff = 1024 + h*64;
  const size_t tb = (size_t)b * 1024;

  __shared__ u16  Qs[64*64];
  __shared__ u16  Ks[64*80];
  __shared__ u16  Vt[64*80];
  __shared__ u16  Ps[64*80];
  __shared__ float Ss[64*65];
  __shared__ float m_l[64], l_l[64], al_l[64];
  __shared__ float red[256], red2[256];

  const int tid  = threadIdx.x;
  const int w    = tid >> 6, lane = tid & 63;
  const int quad = lane >> 4, l16 = lane & 15;

  // stage Q tile (64 tok x 64 d)
#pragma unroll
  for (int r = 0; r < 2; ++r) {
    int flat8 = r*256 + tid;
    int row = flat8 >> 3, c8 = (flat8 & 7) * 8;
    *(u32x4*)&Qs[row*64 + c8] = *(const u32x4*)(qsrc + (tb + qt*64 + row)*2048 + qoff + c8);
  }
  if (tid < 64) { m_l[tid] = -1e30f; l_l[tid] = 0.f; }
  __syncthreads();
  bf16x8 qa0 = *(const bf16x8*)&Qs[(w*16 + l16)*64 + quad*8];
  bf16x8 qa1 = *(const bf16x8*)&Qs[(w*16 + l16)*64 + 32 + quad*8];

  f32x4 oacc[4] = {};
  const int srow = tid >> 2, part = tid & 3;

  for (int kt = 0; kt < 16; ++kt) {
    __syncthreads();
#pragma unroll
    for (int r = 0; r < 2; ++r) {
      int flat8 = r*256 + tid;
      int row = flat8 >> 3, c8 = (flat8 & 7) * 8;
      const u16* kp = kvsrc + (tb + kt*64 + row)*2048 + koff + c8;
      *(u32x4*)&Ks[row*80 + c8] = *(const u32x4*)kp;
      const u16* vp = kvsrc + (tb + kt*64 + row)*2048 + voff + c8;
      u16x8 tv = *(const u16x8*)vp;
#pragma unroll
      for (int jj = 0; jj < 8; ++jj)
        Vt[(c8 + jj)*80 + row] = tv[jj];
    }
    __syncthreads();

    // S = scale * Q K^T  (each wave: 16-row strip x 64 cols)
#pragma unroll
    for (int j = 0; j < 4; ++j) {
      bf16x8 kb0 = *(const bf16x8*)&Ks[(j*16 + l16)*80 + quad*8];
      bf16x8 kb1 = *(const bf16x8*)&Ks[(j*16 + l16)*80 + 32 + quad*8];
      f32x4 s = {};
      s = MFMA16(qa0, kb0, s);
      s = MFMA16(qa1, kb1, s);
#pragma unroll
      for (int reg = 0; reg < 4; ++reg)
        Ss[(w*16 + quad*4 + reg)*65 + j*16 + l16] = s[reg] * SCALE;
    }
    __syncthreads();

    // online softmax: 4 threads per row
    float m_old = m_l[srow];
    float sv[16], mx = -1e30f;
#pragma unroll
    for (int c = 0; c < 16; ++c) { sv[c] = Ss[srow*65 + part*16 + c]; mx = fmaxf(mx, sv[c]); }
    red[tid] = mx;
    __syncthreads();
    float m_new = fmaxf(m_old, fmaxf(fmaxf(red[srow*4], red[srow*4+1]),
                                     fmaxf(red[srow*4+2], red[srow*4+3])));
    float alpha = __expf(m_old - m_new);
    float ls = 0.f;
#pragma unroll
    for (int c = 0; c < 16; ++c) {
      float p = __expf(sv[c] - m_new);
      ls += p;
      Ps[srow*80 + part*16 + c] = f2b(p);
    }
    red2[tid] = ls;
    if (part == 0) { al_l[srow] = alpha; m_l[srow] = m_new; }
    __syncthreads();
    if (part == 0)
      l_l[srow] = alpha*l_l[srow] + red2[srow*4] + red2[srow*4+1] + red2[srow*4+2] + red2[srow*4+3];

    // O = O*alpha + P @ V
    float a0 = al_l[w*16 + quad*4 + 0];
    float a1 = al_l[w*16 + quad*4 + 1];
    float a2 = al_l[w*16 + quad*4 + 2];
    float a3 = al_l[w*16 + quad*4 + 3];
    bf16x8 pa0 = *(const bf16x8*)&Ps[(w*16 + l16)*80 + quad*8];
    bf16x8 pa1 = *(const bf16x8*)&Ps[(w*16 + l16)*80 + 32 + quad*8];
#pragma unroll
    for (int j = 0; j < 4; ++j) {
      oacc[j][0] *= a0; oacc[j][1] *= a1; oacc[j][2] *= a2; oacc[j][3] *= a3;
      bf16x8 vb0 = *(const bf16x8*)&Vt[(j*16 + l16)*80 + quad*8];
      bf16x8 vb1 = *(const bf16x8*)&Vt[(j*16 + l16)*80 + 32 + quad*8];
      oacc[j] = MFMA16(pa0, vb0, oacc[j]);
      oacc[j] = MFMA16(pa1, vb1, oacc[j]);
    }
  }
  __syncthreads();
  u16* aop = ao + (size_t)a * (4096*512);
#pragma unroll
  for (int j = 0; j < 4; ++j)
#pragma unroll
    for (int reg = 0; reg < 4; ++reg) {
      int row = w*16 + quad*4 + reg;
      float ov = oacc[j][reg] / l_l[row];
      aop[(tb + qt*64 + row)*512 + h*64 + j*16 + l16] = f2b(ov);
    }
}

// ---------------- ortho loss via Gram trick ----------------
__global__ __launch_bounds__(256, 2) void ortho_k(
    const u16* __restrict__ qkv1, const u16* __restrict__ qkv2,
    float* __restrict__ accum)
{
  const int bh = blockIdx.x;     // 32
  const int which = blockIdx.y;  // 0: x (qkv1), 1: y (qkv2)
  const u16* src = which ? qkv2 : qkv1;
  const int b = bh >> 3, h = bh & 7;
  const size_t tb = (size_t)b * 1024;

  __shared__ u16 QnT[64*80];
  __shared__ u16 QtnT[64*80];
  __shared__ float reds[256];

  const int tid  = threadIdx.x;
  const int w    = tid >> 6, lane = tid & 63;
  const int quad = lane >> 4, l16 = lane & 15;

  f32x4 gq[4] = {}, gqt[4] = {};
  float diag = 0.f;

  for (int t = 0; t < 16; ++t) {
    __syncthreads();
    if (tid < 128) {
      int tok = t*64 + (tid & 63);
      int c = (tid < 64) ? 0 : 1536;
      const u16* p = src + (tb + tok)*2048 + c + h*64;
      u16x8 rowv[8];
#pragma unroll
      for (int i = 0; i < 8; ++i) rowv[i] = *(const u16x8*)(p + i*8);
      float ss = 0.f;
#pragma unroll
      for (int i = 0; i < 8; ++i)
#pragma unroll
        for (int jj = 0; jj < 8; ++jj) { float f = b2f(rowv[i][jj]); ss += f*f; }
      float inv = 1.f / fmaxf(sqrtf(ss), 1e-12f);
      u16* dst = (tid < 64) ? QnT : QtnT;
#pragma unroll
      for (int i = 0; i < 8; ++i)
#pragma unroll
        for (int jj = 0; jj < 8; ++jj)
          dst[(i*8 + jj)*80 + (tid & 63)] = f2b(b2f(rowv[i][jj]) * inv);
    }
    __syncthreads();
    if (tid < 64) {
      float d = 0.f;
#pragma unroll
      for (int dd = 0; dd < 64; ++dd)
        d += b2f(QnT[dd*80 + tid]) * b2f(QtnT[dd*80 + tid]);
      diag += d * d;
    }
    bf16x8 a0 = *(const bf16x8*)&QnT [(w*16 + l16)*80 + quad*8];
    bf16x8 a1 = *(const bf16x8*)&QnT [(w*16 + l16)*80 + 32 + quad*8];
    bf16x8 t0 = *(const bf16x8*)&QtnT[(w*16 + l16)*80 + quad*8];
    bf16x8 t1 = *(const bf16x8*)&QtnT[(w*16 + l16)*80 + 32 + quad*8];
#pragma unroll
    for (int j = 0; j < 4; ++j) {
      bf16x8 b0 = *(const bf16x8*)&QnT [(j*16 + l16)*80 + quad*8];
      bf16x8 b1 = *(const bf16x8*)&QnT [(j*16 + l16)*80 + 32 + quad*8];
      gq[j]  = MFMA16(a0, b0, gq[j]);
      gq[j]  = MFMA16(a1, b1, gq[j]);
      bf16x8 c0 = *(const bf16x8*)&QtnT[(j*16 + l16)*80 + quad*8];
      bf16x8 c1 = *(const bf16x8*)&QtnT[(j*16 + l16)*80 + 32 + quad*8];
      gqt[j] = MFMA16(t0, c0, gqt[j]);
      gqt[j] = MFMA16(t1, c1, gqt[j]);
    }
  }
  float cross = 0.f;
#pragma unroll
  for (int j = 0; j < 4; ++j)
#pragma unroll
    for (int reg = 0; reg < 4; ++reg) cross += gq[j][reg] * gqt[j][reg];
  reds[tid] = cross - diag;
  __syncthreads();
  for (int s = 128; s > 0; s >>= 1) {
    if (tid < s) reds[tid] += reds[tid + s];
    __syncthreads();
  }
  if (tid == 0) atomicAdd(&accum[which], reds[0]);
}

// ---------------- cosine loss over final xc,yc (f32 in d_out) ----------------
__global__ __launch_bounds__(256, 2) void lc_k(const float* __restrict__ dout,
                                               float* __restrict__ accum)
{
  const int tid = threadIdx.x;
  const int w = tid >> 6, lane = tid & 63;
  const int wid = blockIdx.x * 4 + w;  // 0..255
  float acc = 0.f;
  for (int rr = 0; rr < 16; ++rr) {
    int row = wid*16 + rr;
    const float4* xr = (const float4*)(dout + (size_t)row*512 + lane*8);
    const float4* yr = (const float4*)(dout + 2097152 + (size_t)row*512 + lane*8);
    float4 x0 = xr[0], x1 = xr[1], y0 = yr[0], y1 = yr[1];
    float dxy = x0.x*y0.x + x0.y*y0.y + x0.z*y0.z + x0.w*y0.w
              + x1.x*y1.x + x1.y*y1.y + x1.z*y1.z + x1.w*y1.w;
    float sx  = x0.x*x0.x + x0.y*x0.y + x0.z*x0.z + x0.w*x0.w
              + x1.x*x1.x + x1.y*x1.y + x1.z*x1.z + x1.w*x1.w;
    float sy  = y0.x*y0.x + y0.y*y0.y + y0.z*y0.z + y0.w*y0.w
              + y1.x*y1.x + y1.y*y1.y + y1.z*y1.z + y1.w*y1.w;
#pragma unroll
    for (int off = 32; off > 0; off >>= 1) {
      dxy += __shfl_xor(dxy, off);
      sx  += __shfl_xor(sx,  off);
      sy  += __shfl_xor(sy,  off);
    }
    if (lane == 0) {
      float cosv = dxy / (fmaxf(sqrtf(sx), 1e-12f) * fmaxf(sqrtf(sy), 1e-12f));
      acc += 1.f - cosv;
    }
  }
  if (lane == 0) atomicAdd(&accum[2], acc);
}

__global__ void fin_k(const float* __restrict__ accum, float* __restrict__ outs){
  if (threadIdx.x == 0) {
    outs[0] = accum[0] * (1.f/4194304.f);
    outs[1] = accum[1] * (1.f/4194304.f);
    outs[2] = accum[2] * (1.f/4096.f);
  }
}

extern "C" void kernel_launch(void* const* d_in, const int* in_sizes, int n_in,
                              void* d_out, int out_size, void* d_ws, size_t ws_size,
                              hipStream_t stream)
{
  (void)in_sizes; (void)n_in; (void)out_size; (void)ws_size;
  const float* x     = (const float*)d_in[0];
  const float* y     = (const float*)d_in[1];
  const float* Wqkv1 = (const float*)d_in[2];
  const float* Wqkv2 = (const float*)d_in[3];
  const float* W1 = (const float*)d_in[4];
  const float* b1 = (const float*)d_in[5];
  const float* W2 = (const float*)d_in[6];
  const float* b2 = (const float*)d_in[7];
  const float* W3 = (const float*)d_in[8];
  const float* b3 = (const float*)d_in[9];
  const float* W4 = (const float*)d_in[10];
  const float* b4 = (const float*)d_in[11];

  u16* ws   = (u16*)d_ws;
  u16* xb   = ws;
  u16* yb   = xb   + (size_t)2097152;
  u16* Wq1b = yb   + (size_t)2097152;
  u16* Wq2b = Wq1b + (size_t)1048576;
  u16* W1b  = Wq2b + (size_t)1048576;
  u16* W2b  = W1b + 262144;
  u16* W3b  = W2b + 262144;
  u16* W4b  = W3b + 262144;
  u16* qkv1 = W4b + 262144;
  u16* qkv2 = qkv1 + (size_t)8388608;
  u16* aob  = qkv2 + (size_t)8388608;
  float* accum = (float*)(aob + (size_t)8388608);

  hipMemsetAsync(accum, 0, 16, stream);

  auto cast = [&](const float* s, u16* d, int n){
    int n4 = n >> 2;
    cast_k<<<dim3((n4 + 255) / 256), dim3(256), 0, stream>>>(s, d, n4);
  };
  cast(x, xb, 2097152);
  cast(y, yb, 2097152);
  cast(Wqkv1, Wq1b, 1048576);
  cast(Wqkv2, Wq2b, 1048576);
  cast(W1, W1b, 262144);
  cast(W2, W2b, 262144);
  cast(W3, W3b, 262144);
  cast(W4, W4b, 262144);

  gemm_bt_k<u16><<<dim3(32,16), 256, 0, stream>>>(xb, Wq1b, nullptr, qkv1, 4096, 2048, 512);
  gemm_bt_k<u16><<<dim3(32,16), 256, 0, stream>>>(yb, Wq2b, nullptr, qkv2, 4096, 2048, 512);

  attn_k<<<dim3(16,32,4), 256, 0, stream>>>(qkv1, qkv2, aob);
  ortho_k<<<dim3(32,2), 256, 0, stream>>>(qkv1, qkv2, accum);

  float* outb = (float*)d_out;
  gemm_bt_k<float><<<dim3(32,4), 256, 0, stream>>>(aob,               W1b, b1, outb,               4096, 512, 512);
  gemm_bt_k<float><<<dim3(32,4), 256, 0, stream>>>(aob + 1*2097152,   W2b, b2, outb + 1*2097152,   4096, 512, 512);
  gemm_bt_k<float><<<dim3(32,4), 256, 0, stream>>>(aob + 2*2097152,   W3b, b3, outb + 2*2097152,   4096, 512, 512);
  gemm_bt_k<float><<<dim3(32,4), 256, 0, stream>>>(aob + 3*2097152,   W4b, b4, outb + 3*2097152,   4096, 512, 512);

  lc_k<<<dim3(64), dim3(256), 0, stream>>>(outb, accum);
  fin_k<<<dim3(1), dim3(64), 0, stream>>>(accum, outb + 8388608);
}

// Round 6
// 309.122 us; speedup vs baseline: 1.3701x; 1.3701x over previous
//
#include <hip/hip_runtime.h>

typedef unsigned short u16;
typedef __attribute__((ext_vector_type(4))) unsigned short u16x4;
typedef __attribute__((ext_vector_type(8))) unsigned short u16x8;
typedef __attribute__((ext_vector_type(4))) float          f32x4;
typedef __attribute__((ext_vector_type(8))) __bf16         bf16x8;

#define MFMA16(a,b,c) __builtin_amdgcn_mfma_f32_16x16x32_bf16((a),(b),(c),0,0,0)
#define SCALE 0.125f

__device__ __forceinline__ u16 f2b(float f){
  unsigned u = __builtin_bit_cast(unsigned, f);
  u = (u + 0x7fffu + ((u >> 16) & 1u)) >> 16;
  return (u16)u;
}
__device__ __forceinline__ float b2f(u16 v){
  unsigned u = ((unsigned)v) << 16;
  return __builtin_bit_cast(float, u);
}
__device__ __forceinline__ void async16(const u16* g, u16* l){
  __builtin_amdgcn_global_load_lds(
      (const __attribute__((address_space(1))) unsigned*)g,
      (__attribute__((address_space(3))) unsigned*)l, 16, 0, 0);
}
// XOR-swizzled LDS addressing: 64 u16/row = 8 chunks of 8; conflict-free transposes.
__device__ __forceinline__ int swz(int row, int chunk, int off){
  return row*64 + (((chunk ^ row ^ (row >> 3)) & 7) << 3) + off;
}

// ---------------- fused cast f32 -> bf16 over all 8 inputs ----------------
__global__ void cast_all_k(const float* __restrict__ x, const float* __restrict__ y,
                           const float* __restrict__ wq1, const float* __restrict__ wq2,
                           const float* __restrict__ w1, const float* __restrict__ w2,
                           const float* __restrict__ w3, const float* __restrict__ w4,
                           u16* __restrict__ dst){
  int i = blockIdx.x * 256 + threadIdx.x;            // float4 index, 1,835,008 total
  const float* s; int base;
  if      (i < 524288)  { s = x;   base = 0;       }
  else if (i < 1048576) { s = y;   base = 524288;  }
  else if (i < 1310720) { s = wq1; base = 1048576; }
  else if (i < 1572864) { s = wq2; base = 1310720; }
  else if (i < 1638400) { s = w1;  base = 1572864; }
  else if (i < 1703936) { s = w2;  base = 1638400; }
  else if (i < 1769472) { s = w3;  base = 1703936; }
  else                  { s = w4;  base = 1769472; }
  float4 v = ((const float4*)s)[i - base];
  u16x4 o; o[0]=f2b(v.x); o[1]=f2b(v.y); o[2]=f2b(v.z); o[3]=f2b(v.w);
  ((u16x4*)dst)[i] = o;
}

// ------- batched GEMM: C[M,N] = A[M,K] @ B[N,K]^T (+bias), z batches via strides ----
template <typename OUT>
__global__ __launch_bounds__(256, 2) void gemm_bt_k(
    const u16* __restrict__ A, size_t aStr, const u16* __restrict__ Bm, size_t bStr,
    const float* __restrict__ bias0, const float* __restrict__ bias1,
    const float* __restrict__ bias2, const float* __restrict__ bias3,
    OUT* __restrict__ Cb, size_t cStr, int M, int N, int K)
{
  const int z = blockIdx.z;
  A  += (size_t)z * aStr;  Bm += (size_t)z * bStr;  Cb += (size_t)z * cStr;
  const float* bias = (z==0) ? bias0 : (z==1) ? bias1 : (z==2) ? bias2 : bias3;

  __shared__ u16 As[128*32];
  __shared__ u16 Bs[128*32];
  const int tid  = threadIdx.x;
  const int w    = tid >> 6, lane = tid & 63;
  const int quad = lane >> 4, l16 = lane & 15;
  const int wr   = w >> 1, wc = w & 1;
  const int m0 = blockIdx.x * 128, n0 = blockIdx.y * 128;

  f32x4 acc[4][4] = {};
  const int rowa = lane >> 2;
  const int ko   = (lane & 3) * 8;

  for (int k0 = 0; k0 < K; k0 += 32) {
    __syncthreads();
#pragma unroll
    for (int r = 0; r < 2; ++r) {
      int rb = (r*4 + w) * 16;
      async16(A  + (size_t)(m0 + rb + rowa)*K + k0 + ko, As + (r*4 + w)*512);
      async16(Bm + (size_t)(n0 + rb + rowa)*K + k0 + ko, Bs + (r*4 + w)*512);
    }
    __syncthreads();
    bf16x8 af[4], bfr[4];
#pragma unroll
    for (int i = 0; i < 4; ++i)
      af[i] = *(const bf16x8*)&As[(wr*64 + i*16 + l16)*32 + quad*8];
#pragma unroll
    for (int j = 0; j < 4; ++j)
      bfr[j] = *(const bf16x8*)&Bs[(wc*64 + j*16 + l16)*32 + quad*8];
#pragma unroll
    for (int i = 0; i < 4; ++i)
#pragma unroll
      for (int j = 0; j < 4; ++j)
        acc[i][j] = MFMA16(af[i], bfr[j], acc[i][j]);
  }
#pragma unroll
  for (int j = 0; j < 4; ++j) {
    int col = n0 + wc*64 + j*16 + l16;
    float bv = bias ? bias[col] : 0.0f;
#pragma unroll
    for (int i = 0; i < 4; ++i)
#pragma unroll
      for (int reg = 0; reg < 4; ++reg) {
        int row = m0 + wr*64 + i*16 + quad*4 + reg;
        float v = acc[i][j][reg] + bv;
        if constexpr (__is_same(OUT, float))
          Cb[(size_t)row*N + col] = v;
        else
          Cb[(size_t)row*N + col] = f2b(v);
      }
  }
}

// ---------------- fused flash attention, in-register softmax, swizzled LDS -------
// a=0: xc=attn(qy,kx,vx)  a=1: yc=attn(qx,ky,vy)  a=2: xt=attn(qtx,kx,vx)  a=3: yt=attn(qty,ky,vy)
__global__ __launch_bounds__(256, 4) void attn_k(
    const u16* __restrict__ qkv1, const u16* __restrict__ qkv2,
    u16* __restrict__ ao)
{
  const int qt = blockIdx.x, bh = blockIdx.y, a = blockIdx.z;
  const int b = bh >> 3, h = bh & 7;
  const u16* qsrc  = (a == 1 || a == 2) ? qkv1 : qkv2;
  const u16* kvsrc = (a & 1) ? qkv2 : qkv1;
  const int qoff = ((a >= 2) ? 1536 : 0) + h*64;
  const int koff = 512 + h*64, voff = 1024 + h*64;
  const size_t tb = (size_t)b * 1024;

  __shared__ u16 Ks[4096];   // K[key][d], swizzled
  __shared__ u16 Vt[4096];   // V^T[d][key], swizzled
  __shared__ u16 Ps[4096];   // per-wave 16x64 P buffers

  const int tid = threadIdx.x, w = tid >> 6, lane = tid & 63;
  const int quad = lane >> 4, l16 = lane & 15;

  // Q A-fragments straight from global (A[m=l16][k=quad*8+j] is a plain row segment)
  const u16* qrow = qsrc + (tb + qt*64 + w*16 + l16)*2048 + qoff;
  bf16x8 qa0 = *(const bf16x8*)(qrow + quad*8);
  bf16x8 qa1 = *(const bf16x8*)(qrow + 32 + quad*8);

  f32x4 oacc[4] = {};
  float m_i[4] = {-1e30f, -1e30f, -1e30f, -1e30f};
  float l_i[4] = {0.f, 0.f, 0.f, 0.f};
  u16* myPs = Ps + w*1024;
  const int srow = tid >> 3, schunk = tid & 7;

  for (int kt = 0; kt < 16; ++kt) {
    __syncthreads();                       // prev iter's Ks/Vt reads complete
#pragma unroll
    for (int r = 0; r < 2; ++r) {
      int row = r*32 + srow;               // key index in tile
      const u16* kb = kvsrc + (tb + kt*64 + row)*2048;
      *(u16x8*)&Ks[swz(row, schunk, 0)] = *(const u16x8*)(kb + koff + schunk*8);
      u16x8 tv = *(const u16x8*)(kb + voff + schunk*8);
#pragma unroll
      for (int jj = 0; jj < 8; ++jj)
        Vt[swz(schunk*8 + jj, row >> 3, row & 7)] = tv[jj];   // conflict-free via swizzle
    }
    __syncthreads();

    // S = scale * Q K^T in C-layout: lane holds rows quad*4+reg, keys j*16+l16
    f32x4 s[4];
#pragma unroll
    for (int j = 0; j < 4; ++j) {
      bf16x8 kb0 = *(const bf16x8*)&Ks[swz(j*16 + l16, quad, 0)];
      bf16x8 kb1 = *(const bf16x8*)&Ks[swz(j*16 + l16, quad + 4, 0)];
      f32x4 t = {};
      t = MFMA16(qa0, kb0, t);
      t = MFMA16(qa1, kb1, t);
#pragma unroll
      for (int reg = 0; reg < 4; ++reg) s[j][reg] = t[reg] * SCALE;
    }

    // in-register online softmax (row reductions = shfl over l16 within quad)
    float alpha[4];
#pragma unroll
    for (int reg = 0; reg < 4; ++reg) {
      float mx = fmaxf(fmaxf(s[0][reg], s[1][reg]), fmaxf(s[2][reg], s[3][reg]));
      mx = fmaxf(mx, __shfl_xor(mx, 1));
      mx = fmaxf(mx, __shfl_xor(mx, 2));
      mx = fmaxf(mx, __shfl_xor(mx, 4));
      mx = fmaxf(mx, __shfl_xor(mx, 8));
      float mn = fmaxf(m_i[reg], mx);
      alpha[reg] = __expf(m_i[reg] - mn);
      m_i[reg] = mn;
      float ls = 0.f;
#pragma unroll
      for (int j = 0; j < 4; ++j) {
        float p = __expf(s[j][reg] - mn);
        s[j][reg] = p;
        ls += p;
      }
      ls += __shfl_xor(ls, 1);
      ls += __shfl_xor(ls, 2);
      ls += __shfl_xor(ls, 4);
      ls += __shfl_xor(ls, 8);
      l_i[reg] = alpha[reg]*l_i[reg] + ls;
    }

    // P -> own LDS buffer (C-layout -> A-layout transform; no barrier needed)
#pragma unroll
    for (int j = 0; j < 4; ++j)
#pragma unroll
      for (int reg = 0; reg < 4; ++reg)
        myPs[swz(quad*4 + reg, j*2 + (l16 >> 3), l16 & 7)] = f2b(s[j][reg]);

    bf16x8 pa0 = *(const bf16x8*)&myPs[swz(l16, quad, 0)];
    bf16x8 pa1 = *(const bf16x8*)&myPs[swz(l16, quad + 4, 0)];
#pragma unroll
    for (int j = 0; j < 4; ++j) {
      bf16x8 vb0 = *(const bf16x8*)&Vt[swz(j*16 + l16, quad, 0)];
      bf16x8 vb1 = *(const bf16x8*)&Vt[swz(j*16 + l16, quad + 4, 0)];
#pragma unroll
      for (int reg = 0; reg < 4; ++reg) oacc[j][reg] *= alpha[reg];
      oacc[j] = MFMA16(pa0, vb0, oacc[j]);
      oacc[j] = MFMA16(pa1, vb1, oacc[j]);
    }
  }

  u16* aop = ao + (size_t)a*(4096*512) + (tb + qt*64)*512 + h*64;
#pragma unroll
  for (int j = 0; j < 4; ++j)
#pragma unroll
    for (int reg = 0; reg < 4; ++reg) {
      int row = w*16 + quad*4 + reg;
      aop[(size_t)row*512 + j*16 + l16] = f2b(oacc[j][reg] / l_i[reg]);
    }
}

// ---------------- ortho loss, two-phase Gram ----------------
// Phase A: grid (32 bh, 2 which, 4 tgroup): partial Grams -> atomicAdd into Gbuf;
//          diag term (sum_n (qn.qtn)^2) computed in registers, subtracted from accum.
__global__ __launch_bounds__(256, 2) void orthoA_k(
    const u16* __restrict__ qkv1, const u16* __restrict__ qkv2,
    float* __restrict__ Gbuf, float* __restrict__ accum)
{
  const int bh = blockIdx.x, which = blockIdx.y, tg = blockIdx.z;
  const u16* src = which ? qkv2 : qkv1;
  const int b = bh >> 3, h = bh & 7;
  const size_t tb = (size_t)b * 1024;

  __shared__ u16 QnT[4096], QtnT[4096];
  const int tid = threadIdx.x, w = tid >> 6, lane = tid & 63;
  const int quad = lane >> 4, l16 = lane & 15;

  f32x4 gq[4] = {}, gqt[4] = {};
  float diag = 0.f;

  for (int tt = 0; tt < 4; ++tt) {
    int t = tg*4 + tt;
    __syncthreads();
    if (tid < 128) {
      int tok = tid & 63, mat = tid >> 6;
      const u16* p = src + (tb + t*64 + tok)*2048 + (mat ? 1536 : 0) + h*64;
      u16x8 rowv[8];
#pragma unroll
      for (int i = 0; i < 8; ++i) rowv[i] = *(const u16x8*)(p + i*8);
      float ss = 0.f;
#pragma unroll
      for (int i = 0; i < 8; ++i)
#pragma unroll
        for (int jj = 0; jj < 8; ++jj) { float f = b2f(rowv[i][jj]); ss += f*f; }
      float inv = 1.f / fmaxf(sqrtf(ss), 1e-12f);
      u16* dst = mat ? QtnT : QnT;
#pragma unroll
      for (int i = 0; i < 8; ++i)
#pragma unroll
        for (int jj = 0; jj < 8; ++jj)
          dst[swz(i*8 + jj, tok >> 3, tok & 7)] = f2b(b2f(rowv[i][jj]) * inv);
      if (mat == 0) {   // diag contribution from raw rows, all in registers
        const u16* p2 = src + (tb + t*64 + tok)*2048 + 1536 + h*64;
        float ss2 = 0.f, dot = 0.f;
#pragma unroll
        for (int i = 0; i < 8; ++i) {
          u16x8 r2 = *(const u16x8*)(p2 + i*8);
#pragma unroll
          for (int jj = 0; jj < 8; ++jj) {
            float fq = b2f(rowv[i][jj]), ft = b2f(r2[jj]);
            ss2 += ft*ft; dot += fq*ft;
          }
        }
        float inv2 = 1.f / fmaxf(sqrtf(ss2), 1e-12f);
        float dn = dot * inv * inv2;
        diag += dn * dn;
      }
    }
    __syncthreads();
    bf16x8 a0 = *(const bf16x8*)&QnT [swz(w*16 + l16, quad, 0)];
    bf16x8 a1 = *(const bf16x8*)&QnT [swz(w*16 + l16, quad + 4, 0)];
    bf16x8 t0 = *(const bf16x8*)&QtnT[swz(w*16 + l16, quad, 0)];
    bf16x8 t1 = *(const bf16x8*)&QtnT[swz(w*16 + l16, quad + 4, 0)];
#pragma unroll
    for (int j = 0; j < 4; ++j) {
      bf16x8 b0 = *(const bf16x8*)&QnT [swz(j*16 + l16, quad, 0)];
      bf16x8 b1 = *(const bf16x8*)&QnT [swz(j*16 + l16, quad + 4, 0)];
      gq[j]  = MFMA16(a0, b0, gq[j]);
      gq[j]  = MFMA16(a1, b1, gq[j]);
      bf16x8 c0 = *(const bf16x8*)&QtnT[swz(j*16 + l16, quad, 0)];
      bf16x8 c1 = *(const bf16x8*)&QtnT[swz(j*16 + l16, quad + 4, 0)];
      gqt[j] = MFMA16(t0, c0, gqt[j]);
      gqt[j] = MFMA16(t1, c1, gqt[j]);
    }
  }
  float* Gq = Gbuf + (size_t)((which*32 + bh)*2) * 4096;
  float* Gt = Gq + 4096;
#pragma unroll
  for (int j = 0; j < 4; ++j)
#pragma unroll
    for (int reg = 0; reg < 4; ++reg) {
      int row = w*16 + quad*4 + reg, col = j*16 + l16;
      atomicAdd(&Gq[row*64 + col], gq[j][reg]);
      atomicAdd(&Gt[row*64 + col], gqt[j][reg]);
    }
  if (tid < 64) atomicAdd(&accum[which], -diag);
}

// Phase B: <Gq, Gqt> per (bh, which)
__global__ void orthoB_k(const float* __restrict__ Gbuf, float* __restrict__ accum){
  const int bh = blockIdx.x, which = blockIdx.y;
  const float* Gq = Gbuf + (size_t)((which*32 + bh)*2) * 4096;
  const float* Gt = Gq + 4096;
  const int tid = threadIdx.x;
  float acc = 0.f;
  for (int i = tid*4; i < 4096; i += 1024) {
    float4 g  = *(const float4*)(Gq + i);
    float4 gt = *(const float4*)(Gt + i);
    acc += g.x*gt.x + g.y*gt.y + g.z*gt.z + g.w*gt.w;
  }
  __shared__ float red[256];
  red[tid] = acc; __syncthreads();
  for (int s2 = 128; s2 > 0; s2 >>= 1) {
    if (tid < s2) red[tid] += red[tid + s2];
    __syncthreads();
  }
  if (tid == 0) atomicAdd(&accum[which], red[0]);
}

// ---------------- cosine loss over final xc,yc (f32 in d_out) ----------------
__global__ __launch_bounds__(256, 2) void lc_k(const float* __restrict__ dout,
                                               float* __restrict__ accum)
{
  const int tid = threadIdx.x;
  const int w = tid >> 6, lane = tid & 63;
  const int wid = blockIdx.x * 4 + w;
  float acc = 0.f;
  for (int rr = 0; rr < 16; ++rr) {
    int row = wid*16 + rr;
    const float4* xr = (const float4*)(dout + (size_t)row*512 + lane*8);
    const float4* yr = (const float4*)(dout + 2097152 + (size_t)row*512 + lane*8);
    float4 x0 = xr[0], x1 = xr[1], y0 = yr[0], y1 = yr[1];
    float dxy = x0.x*y0.x + x0.y*y0.y + x0.z*y0.z + x0.w*y0.w
              + x1.x*y1.x + x1.y*y1.y + x1.z*y1.z + x1.w*y1.w;
    float sx  = x0.x*x0.x + x0.y*x0.y + x0.z*x0.z + x0.w*x0.w
              + x1.x*x1.x + x1.y*x1.y + x1.z*x1.z + x1.w*x1.w;
    float sy  = y0.x*y0.x + y0.y*y0.y + y0.z*y0.z + y0.w*y0.w
              + y1.x*y1.x + y1.y*y1.y + y1.z*y1.z + y1.w*y1.w;
#pragma unroll
    for (int off = 32; off > 0; off >>= 1) {
      dxy += __shfl_xor(dxy, off);
      sx  += __shfl_xor(sx,  off);
      sy  += __shfl_xor(sy,  off);
    }
    if (lane == 0) {
      float cosv = dxy / (fmaxf(sqrtf(sx), 1e-12f) * fmaxf(sqrtf(sy), 1e-12f));
      acc += 1.f - cosv;
    }
  }
  if (lane == 0) atomicAdd(&accum[2], acc);
}

__global__ void fin_k(const float* __restrict__ accum, float* __restrict__ outs){
  if (threadIdx.x == 0) {
    outs[0] = accum[0] * (1.f/4194304.f);
    outs[1] = accum[1] * (1.f/4194304.f);
    outs[2] = accum[2] * (1.f/4096.f);
  }
}

extern "C" void kernel_launch(void* const* d_in, const int* in_sizes, int n_in,
                              void* d_out, int out_size, void* d_ws, size_t ws_size,
                              hipStream_t stream)
{
  (void)in_sizes; (void)n_in; (void)out_size; (void)ws_size;
  const float* x     = (const float*)d_in[0];
  const float* y     = (const float*)d_in[1];
  const float* Wqkv1 = (const float*)d_in[2];
  const float* Wqkv2 = (const float*)d_in[3];
  const float* W1 = (const float*)d_in[4];
  const float* b1 = (const float*)d_in[5];
  const float* W2 = (const float*)d_in[6];
  const float* b2 = (const float*)d_in[7];
  const float* W3 = (const float*)d_in[8];
  const float* b3 = (const float*)d_in[9];
  const float* W4 = (const float*)d_in[10];
  const float* b4 = (const float*)d_in[11];

  u16* ws   = (u16*)d_ws;
  u16* xb   = ws;                                  // 2097152
  u16* Wq1b = ws + (size_t)4194304;                // 1048576
  u16* W1b  = ws + (size_t)6291456;                // 4 x 262144
  u16* qkv1 = ws + (size_t)7340032;                // 8388608
  u16* qkv2 = qkv1 + (size_t)8388608;
  u16* aob  = qkv2 + (size_t)8388608;              // 4 x 2097152
  float* accum = (float*)(aob + (size_t)8388608);
  float* Gbuf  = accum + 16;                       // 2 MB

  hipMemsetAsync(accum, 0, 16, stream);
  hipMemsetAsync(Gbuf, 0, 2097152, stream);

  cast_all_k<<<dim3(7168), dim3(256), 0, stream>>>(x, y, Wqkv1, Wqkv2, W1, W2, W3, W4, xb);

  gemm_bt_k<u16><<<dim3(32,16,2), 256, 0, stream>>>(
      xb, 2097152, Wq1b, 1048576, nullptr, nullptr, nullptr, nullptr,
      qkv1, 8388608, 4096, 2048, 512);

  attn_k<<<dim3(16,32,4), 256, 0, stream>>>(qkv1, qkv2, aob);

  orthoA_k<<<dim3(32,2,4), 256, 0, stream>>>(qkv1, qkv2, Gbuf, accum);

  float* outb = (float*)d_out;
  gemm_bt_k<float><<<dim3(32,4,4), 256, 0, stream>>>(
      aob, 2097152, W1b, 262144, b1, b2, b3, b4,
      outb, 2097152, 4096, 512, 512);

  orthoB_k<<<dim3(32,2), 256, 0, stream>>>(Gbuf, accum);
  lc_k<<<dim3(64), dim3(256), 0, stream>>>(outb, accum);
  fin_k<<<dim3(1), dim3(64), 0, stream>>>(accum, outb + 8388608);
}

// Round 7
// 270.236 us; speedup vs baseline: 1.5673x; 1.1439x over previous
//
#include <hip/hip_runtime.h>

typedef unsigned short u16;
typedef __attribute__((ext_vector_type(4))) unsigned short u16x4;
typedef __attribute__((ext_vector_type(8))) unsigned short u16x8;
typedef __attribute__((ext_vector_type(4))) float          f32x4;
typedef __attribute__((ext_vector_type(8))) __bf16         bf16x8;

#define MFMA16(a,b,c) __builtin_amdgcn_mfma_f32_16x16x32_bf16((a),(b),(c),0,0,0)
#define SCALE 0.125f

__device__ __forceinline__ u16 f2b(float f){
  unsigned u = __builtin_bit_cast(unsigned, f);
  u = (u + 0x7fffu + ((u >> 16) & 1u)) >> 16;
  return (u16)u;
}
__device__ __forceinline__ float b2f(u16 v){
  unsigned u = ((unsigned)v) << 16;
  return __builtin_bit_cast(float, u);
}
__device__ __forceinline__ void async16(const u16* g, u16* l){
  __builtin_amdgcn_global_load_lds(
      (const __attribute__((address_space(1))) unsigned*)g,
      (__attribute__((address_space(3))) unsigned*)l, 16, 0, 0);
}
// XOR-swizzled LDS addressing: rows of 64 u16 = 8 chunks of 8; conflict-free transposes.
__device__ __forceinline__ int swz(int row, int chunk, int off){
  return row*64 + (((chunk ^ row ^ (row >> 3)) & 7) << 3) + off;
}

// ---------------- fused cast f32 -> bf16 over all 8 inputs ----------------
__global__ void cast_all_k(const float* __restrict__ x, const float* __restrict__ y,
                           const float* __restrict__ wq1, const float* __restrict__ wq2,
                           const float* __restrict__ w1, const float* __restrict__ w2,
                           const float* __restrict__ w3, const float* __restrict__ w4,
                           u16* __restrict__ dst){
  int i = blockIdx.x * 256 + threadIdx.x;            // float4 index, 1,835,008 total
  const float* s; int base;
  if      (i < 524288)  { s = x;   base = 0;       }
  else if (i < 1048576) { s = y;   base = 524288;  }
  else if (i < 1310720) { s = wq1; base = 1048576; }
  else if (i < 1572864) { s = wq2; base = 1310720; }
  else if (i < 1638400) { s = w1;  base = 1572864; }
  else if (i < 1703936) { s = w2;  base = 1638400; }
  else if (i < 1769472) { s = w3;  base = 1703936; }
  else                  { s = w4;  base = 1769472; }
  float4 v = ((const float4*)s)[i - base];
  u16x4 o; o[0]=f2b(v.x); o[1]=f2b(v.y); o[2]=f2b(v.z); o[3]=f2b(v.w);
  ((u16x4*)dst)[i] = o;
}

// ------- batched GEMM: C[M,N] = A[M,K] @ B[N,K]^T (+bias), z batches, ldc stride ----
template <typename OUT>
__global__ __launch_bounds__(256, 2) void gemm_bt_k(
    const u16* __restrict__ A, size_t aStr, const u16* __restrict__ Bm, size_t bStr,
    const float* __restrict__ bias0, const float* __restrict__ bias1,
    const float* __restrict__ bias2, const float* __restrict__ bias3,
    OUT* __restrict__ Cb, size_t cStr, int M, int N, int K, int ldc)
{
  const int z = blockIdx.z;
  A  += (size_t)z * aStr;  Bm += (size_t)z * bStr;  Cb += (size_t)z * cStr;
  const float* bias = (z==0) ? bias0 : (z==1) ? bias1 : (z==2) ? bias2 : bias3;

  __shared__ u16 As[128*32];
  __shared__ u16 Bs[128*32];
  const int tid  = threadIdx.x;
  const int w    = tid >> 6, lane = tid & 63;
  const int quad = lane >> 4, l16 = lane & 15;
  const int wr   = w >> 1, wc = w & 1;
  const int m0 = blockIdx.x * 128, n0 = blockIdx.y * 128;

  f32x4 acc[4][4] = {};
  const int rowa = lane >> 2;
  const int ko   = (lane & 3) * 8;

  for (int k0 = 0; k0 < K; k0 += 32) {
    __syncthreads();
#pragma unroll
    for (int r = 0; r < 2; ++r) {
      int rb = (r*4 + w) * 16;
      async16(A  + (size_t)(m0 + rb + rowa)*K + k0 + ko, As + (r*4 + w)*512);
      async16(Bm + (size_t)(n0 + rb + rowa)*K + k0 + ko, Bs + (r*4 + w)*512);
    }
    __syncthreads();
    bf16x8 af[4], bfr[4];
#pragma unroll
    for (int i = 0; i < 4; ++i)
      af[i] = *(const bf16x8*)&As[(wr*64 + i*16 + l16)*32 + quad*8];
#pragma unroll
    for (int j = 0; j < 4; ++j)
      bfr[j] = *(const bf16x8*)&Bs[(wc*64 + j*16 + l16)*32 + quad*8];
#pragma unroll
    for (int i = 0; i < 4; ++i)
#pragma unroll
      for (int j = 0; j < 4; ++j)
        acc[i][j] = MFMA16(af[i], bfr[j], acc[i][j]);
  }
#pragma unroll
  for (int j = 0; j < 4; ++j) {
    int col = n0 + wc*64 + j*16 + l16;
    float bv = bias ? bias[col] : 0.0f;
#pragma unroll
    for (int i = 0; i < 4; ++i)
#pragma unroll
      for (int reg = 0; reg < 4; ++reg) {
        int row = m0 + wr*64 + i*16 + quad*4 + reg;
        float v = acc[i][j][reg] + bv;
        if constexpr (__is_same(OUT, float))
          Cb[(size_t)row*ldc + col] = v;
        else
          Cb[(size_t)row*ldc + col] = f2b(v);
      }
  }
}

// ---------------- flash attention: S^T-form MFMA, fixed-shift softmax -------------
// a=0: xc=attn(qy,kx,vx)  a=1: yc=attn(qx,ky,vy)  a=2: xt=attn(qtx,kx,vx)  a=3: yt=attn(qty,ky,vy)
// Block: 128 qrows (4 waves x 2 strips x 16 rows). K tiles of 64 keys, 16 iters.
__global__ __launch_bounds__(256, 4) void attn_k(
    const u16* __restrict__ qkv1, const u16* __restrict__ qkv2,
    const u16* __restrict__ vT1, const u16* __restrict__ vT2,
    u16* __restrict__ ao)
{
  const int qt = blockIdx.x, bh = blockIdx.y, a = blockIdx.z;
  const int b = bh >> 3, h = bh & 7;
  const u16* qsrc  = (a == 1 || a == 2) ? qkv1 : qkv2;
  const u16* kvsrc = (a & 1) ? qkv2 : qkv1;
  const u16* vsrc  = (a & 1) ? vT2 : vT1;
  const int qoff = ((a >= 2) ? 1536 : 0) + h*64;
  const int koff = 512 + h*64;
  const size_t tb = (size_t)b * 1024;

  __shared__ u16 Ks[4096];   // K[key][d], swizzled
  __shared__ u16 Vt[4096];   // V^T[d][key], swizzled
  __shared__ u16 Ps[8192];   // per-wave, per-strip P[qrow][key], swizzled

  const int tid = threadIdx.x, w = tid >> 6, lane = tid & 63;
  const int quad = lane >> 4, l16 = lane & 15;
  const int srow = tid >> 3, sch = tid & 7;     // staging: 256 thr cover 32 rows x 8 chunks

  // Q B-frags for 2 strips (qrow = qt*128 + w*32 + strip*16 + l16)
  bf16x8 qb[2][2];
#pragma unroll
  for (int s2 = 0; s2 < 2; ++s2) {
    const u16* qr = qsrc + (tb + qt*128 + w*32 + s2*16 + l16)*2048 + qoff;
    qb[s2][0] = *(const bf16x8*)(qr + quad*8);
    qb[s2][1] = *(const bf16x8*)(qr + 32 + quad*8);
  }

  f32x4 oacc[2][4] = {};
  float lpart[2] = {0.f, 0.f};
  u16* myP = Ps + w*2048;

  // prefetch tile 0 into registers
  u16x8 kreg[2], vreg[2];
  {
    kreg[0] = *(const u16x8*)(kvsrc + (tb + srow)*2048 + koff + sch*8);
    kreg[1] = *(const u16x8*)(kvsrc + (tb + 32 + srow)*2048 + koff + sch*8);
    vreg[0] = *(const u16x8*)(vsrc + (size_t)(h*64 + srow)*4096 + tb + sch*8);
    vreg[1] = *(const u16x8*)(vsrc + (size_t)(h*64 + 32 + srow)*4096 + tb + sch*8);
  }

  for (int kt = 0; kt < 16; ++kt) {
    __syncthreads();                       // prior tile's reads complete
    *(u16x8*)&Ks[swz(srow,      sch, 0)] = kreg[0];
    *(u16x8*)&Ks[swz(32 + srow, sch, 0)] = kreg[1];
    *(u16x8*)&Vt[swz(srow,      sch, 0)] = vreg[0];
    *(u16x8*)&Vt[swz(32 + srow, sch, 0)] = vreg[1];
    if (kt < 15) {                         // prefetch next tile (in flight over compute)
      kreg[0] = *(const u16x8*)(kvsrc + (tb + (kt+1)*64 + srow)*2048 + koff + sch*8);
      kreg[1] = *(const u16x8*)(kvsrc + (tb + (kt+1)*64 + 32 + srow)*2048 + koff + sch*8);
      vreg[0] = *(const u16x8*)(vsrc + (size_t)(h*64 + srow)*4096 + tb + (kt+1)*64 + sch*8);
      vreg[1] = *(const u16x8*)(vsrc + (size_t)(h*64 + 32 + srow)*4096 + tb + (kt+1)*64 + sch*8);
    }
    __syncthreads();

    // S^T = K @ Q^T (D rows = keys, cols = qrows); then p = exp(s*SCALE) in-register
#pragma unroll
    for (int j = 0; j < 4; ++j) {
      bf16x8 ka0 = *(const bf16x8*)&Ks[swz(j*16 + l16, quad, 0)];
      bf16x8 ka1 = *(const bf16x8*)&Ks[swz(j*16 + l16, quad + 4, 0)];
#pragma unroll
      for (int s2 = 0; s2 < 2; ++s2) {
        f32x4 t = {};
        t = MFMA16(ka0, qb[s2][0], t);
        t = MFMA16(ka1, qb[s2][1], t);
        u16x4 pk;
#pragma unroll
        for (int reg = 0; reg < 4; ++reg) {
          float p = __expf(t[reg] * SCALE);
          lpart[s2] += p;
          pk[reg] = f2b(p);
        }
        // P[qrow=l16][key=j*16+quad*4+reg] packed b64 (chunk=j*2+(quad>>1), off=(quad&1)*4)
        *(u16x4*)&myP[s2*1024 + swz(l16, j*2 + (quad >> 1), (quad & 1)*4)] = pk;
      }
    }

    // O += P @ V  (A = P rows qrow, B = Vt rows d)
    bf16x8 pa[2][2];
#pragma unroll
    for (int s2 = 0; s2 < 2; ++s2) {
      pa[s2][0] = *(const bf16x8*)&myP[s2*1024 + swz(l16, quad, 0)];
      pa[s2][1] = *(const bf16x8*)&myP[s2*1024 + swz(l16, quad + 4, 0)];
    }
#pragma unroll
    for (int j = 0; j < 4; ++j) {
      bf16x8 vb0 = *(const bf16x8*)&Vt[swz(j*16 + l16, quad, 0)];
      bf16x8 vb1 = *(const bf16x8*)&Vt[swz(j*16 + l16, quad + 4, 0)];
#pragma unroll
      for (int s2 = 0; s2 < 2; ++s2) {
        oacc[s2][j] = MFMA16(pa[s2][0], vb0, oacc[s2][j]);
        oacc[s2][j] = MFMA16(pa[s2][1], vb1, oacc[s2][j]);
      }
    }
  }

  // epilogue: reduce l over quad copies, normalize, store
  u16* aop = ao + (size_t)a*(4096*512) + (tb + qt*128)*512 + h*64;
#pragma unroll
  for (int s2 = 0; s2 < 2; ++s2) {
    float lt = lpart[s2];
    lt += __shfl_xor(lt, 16);
    lt += __shfl_xor(lt, 32);              // all quad copies of qrow l16 now hold full sum
#pragma unroll
    for (int reg = 0; reg < 4; ++reg) {
      float lrow = __shfl(lt, quad*4 + reg);   // l for qrow quad*4+reg (lane has l16==that)
      float linv = 1.f / lrow;
      int row = w*32 + s2*16 + quad*4 + reg;
#pragma unroll
      for (int j = 0; j < 4; ++j)
        aop[(size_t)row*512 + j*16 + l16] = f2b(oacc[s2][j][reg] * linv);
    }
  }
}

// ---------------- ortho loss, two-phase Gram ----------------
__global__ __launch_bounds__(256, 2) void orthoA_k(
    const u16* __restrict__ qkv1, const u16* __restrict__ qkv2,
    float* __restrict__ Gbuf, float* __restrict__ accum)
{
  const int bh = blockIdx.x, which = blockIdx.y, tg = blockIdx.z;
  const u16* src = which ? qkv2 : qkv1;
  const int b = bh >> 3, h = bh & 7;
  const size_t tb = (size_t)b * 1024;

  __shared__ u16 QnT[4096], QtnT[4096];
  const int tid = threadIdx.x, w = tid >> 6, lane = tid & 63;
  const int quad = lane >> 4, l16 = lane & 15;

  f32x4 gq[4] = {}, gqt[4] = {};
  float diag = 0.f;

  for (int tt = 0; tt < 4; ++tt) {
    int t = tg*4 + tt;
    __syncthreads();
    if (tid < 128) {
      int tok = tid & 63, mat = tid >> 6;
      const u16* p = src + (tb + t*64 + tok)*2048 + (mat ? 1536 : 0) + h*64;
      u16x8 rowv[8];
#pragma unroll
      for (int i = 0; i < 8; ++i) rowv[i] = *(const u16x8*)(p + i*8);
      float ss = 0.f;
#pragma unroll
      for (int i = 0; i < 8; ++i)
#pragma unroll
        for (int jj = 0; jj < 8; ++jj) { float f = b2f(rowv[i][jj]); ss += f*f; }
      float inv = 1.f / fmaxf(sqrtf(ss), 1e-12f);
      u16* dst = mat ? QtnT : QnT;
#pragma unroll
      for (int i = 0; i < 8; ++i)
#pragma unroll
        for (int jj = 0; jj < 8; ++jj)
          dst[swz(i*8 + jj, tok >> 3, tok & 7)] = f2b(b2f(rowv[i][jj]) * inv);
      if (mat == 0) {
        const u16* p2 = src + (tb + t*64 + tok)*2048 + 1536 + h*64;
        float ss2 = 0.f, dot = 0.f;
#pragma unroll
        for (int i = 0; i < 8; ++i) {
          u16x8 r2 = *(const u16x8*)(p2 + i*8);
#pragma unroll
          for (int jj = 0; jj < 8; ++jj) {
            float fq = b2f(rowv[i][jj]), ft = b2f(r2[jj]);
            ss2 += ft*ft; dot += fq*ft;
          }
        }
        float inv2 = 1.f / fmaxf(sqrtf(ss2), 1e-12f);
        float dn = dot * inv * inv2;
        diag += dn * dn;
      }
    }
    __syncthreads();
    bf16x8 a0 = *(const bf16x8*)&QnT [swz(w*16 + l16, quad, 0)];
    bf16x8 a1 = *(const bf16x8*)&QnT [swz(w*16 + l16, quad + 4, 0)];
    bf16x8 t0 = *(const bf16x8*)&QtnT[swz(w*16 + l16, quad, 0)];
    bf16x8 t1 = *(const bf16x8*)&QtnT[swz(w*16 + l16, quad + 4, 0)];
#pragma unroll
    for (int j = 0; j < 4; ++j) {
      bf16x8 b0 = *(const bf16x8*)&QnT [swz(j*16 + l16, quad, 0)];
      bf16x8 b1 = *(const bf16x8*)&QnT [swz(j*16 + l16, quad + 4, 0)];
      gq[j]  = MFMA16(a0, b0, gq[j]);
      gq[j]  = MFMA16(a1, b1, gq[j]);
      bf16x8 c0 = *(const bf16x8*)&QtnT[swz(j*16 + l16, quad, 0)];
      bf16x8 c1 = *(const bf16x8*)&QtnT[swz(j*16 + l16, quad + 4, 0)];
      gqt[j] = MFMA16(t0, c0, gqt[j]);
      gqt[j] = MFMA16(t1, c1, gqt[j]);
    }
  }
  float* Gq = Gbuf + (size_t)((which*32 + bh)*2) * 4096;
  float* Gt = Gq + 4096;
#pragma unroll
  for (int j = 0; j < 4; ++j)
#pragma unroll
    for (int reg = 0; reg < 4; ++reg) {
      int row = w*16 + quad*4 + reg, col = j*16 + l16;
      atomicAdd(&Gq[row*64 + col], gq[j][reg]);
      atomicAdd(&Gt[row*64 + col], gqt[j][reg]);
    }
  if (tid < 64) atomicAdd(&accum[which], -diag);
}

__global__ void orthoB_k(const float* __restrict__ Gbuf, float* __restrict__ accum){
  const int bh = blockIdx.x, which = blockIdx.y;
  const float* Gq = Gbuf + (size_t)((which*32 + bh)*2) * 4096;
  const float* Gt = Gq + 4096;
  const int tid = threadIdx.x;
  float acc = 0.f;
  for (int i = tid*4; i < 4096; i += 1024) {
    float4 g  = *(const float4*)(Gq + i);
    float4 gt = *(const float4*)(Gt + i);
    acc += g.x*gt.x + g.y*gt.y + g.z*gt.z + g.w*gt.w;
  }
  __shared__ float red[256];
  red[tid] = acc; __syncthreads();
  for (int s2 = 128; s2 > 0; s2 >>= 1) {
    if (tid < s2) red[tid] += red[tid + s2];
    __syncthreads();
  }
  if (tid == 0) atomicAdd(&accum[which], red[0]);
}

// ---------------- cosine loss over final xc,yc (f32 in d_out) ----------------
__global__ __launch_bounds__(256, 2) void lc_k(const float* __restrict__ dout,
                                               float* __restrict__ accum)
{
  const int tid = threadIdx.x;
  const int w = tid >> 6, lane = tid & 63;
  const int wid = blockIdx.x * 4 + w;
  float acc = 0.f;
  for (int rr = 0; rr < 16; ++rr) {
    int row = wid*16 + rr;
    const float4* xr = (const float4*)(dout + (size_t)row*512 + lane*8);
    const float4* yr = (const float4*)(dout + 2097152 + (size_t)row*512 + lane*8);
    float4 x0 = xr[0], x1 = xr[1], y0 = yr[0], y1 = yr[1];
    float dxy = x0.x*y0.x + x0.y*y0.y + x0.z*y0.z + x0.w*y0.w
              + x1.x*y1.x + x1.y*y1.y + x1.z*y1.z + x1.w*y1.w;
    float sx  = x0.x*x0.x + x0.y*x0.y + x0.z*x0.z + x0.w*x0.w
              + x1.x*x1.x + x1.y*x1.y + x1.z*x1.z + x1.w*x1.w;
    float sy  = y0.x*y0.x + y0.y*y0.y + y0.z*y0.z + y0.w*y0.w
              + y1.x*y1.x + y1.y*y1.y + y1.z*y1.z + y1.w*y1.w;
#pragma unroll
    for (int off = 32; off > 0; off >>= 1) {
      dxy += __shfl_xor(dxy, off);
      sx  += __shfl_xor(sx,  off);
      sy  += __shfl_xor(sy,  off);
    }
    if (lane == 0) {
      float cosv = dxy / (fmaxf(sqrtf(sx), 1e-12f) * fmaxf(sqrtf(sy), 1e-12f));
      acc += 1.f - cosv;
    }
  }
  if (lane == 0) atomicAdd(&accum[2], acc);
}

__global__ void fin_k(const float* __restrict__ accum, float* __restrict__ outs){
  if (threadIdx.x == 0) {
    outs[0] = accum[0] * (1.f/4194304.f);
    outs[1] = accum[1] * (1.f/4194304.f);
    outs[2] = accum[2] * (1.f/4096.f);
  }
}

extern "C" void kernel_launch(void* const* d_in, const int* in_sizes, int n_in,
                              void* d_out, int out_size, void* d_ws, size_t ws_size,
                              hipStream_t stream)
{
  (void)in_sizes; (void)n_in; (void)out_size; (void)ws_size;
  const float* x     = (const float*)d_in[0];
  const float* y     = (const float*)d_in[1];
  const float* Wqkv1 = (const float*)d_in[2];
  const float* Wqkv2 = (const float*)d_in[3];
  const float* W1 = (const float*)d_in[4];
  const float* b1 = (const float*)d_in[5];
  const float* W2 = (const float*)d_in[6];
  const float* b2 = (const float*)d_in[7];
  const float* W3 = (const float*)d_in[8];
  const float* b3 = (const float*)d_in[9];
  const float* W4 = (const float*)d_in[10];
  const float* b4 = (const float*)d_in[11];

  u16* ws   = (u16*)d_ws;
  u16* xb   = ws;                                  // x,y: 2 x 2097152
  u16* Wq1b = ws + (size_t)4194304;                // 2 x 1048576
  u16* W1b  = ws + (size_t)6291456;                // 4 x 262144
  u16* qkv1 = ws + (size_t)7340032;                // 2 x 8388608
  u16* qkv2 = qkv1 + (size_t)8388608;
  u16* aob  = qkv2 + (size_t)8388608;              // 4 x 2097152
  float* accum = (float*)(aob + (size_t)8388608);
  float* Gbuf  = accum + 16;                       // 2 MB
  // V^T buffers live in d_out (consumed by attn_k before final GEMM overwrites)
  u16* vT1 = (u16*)d_out;                          // 512 x 4096
  u16* vT2 = vT1 + (size_t)2097152;

  hipMemsetAsync(accum, 0, 16, stream);
  hipMemsetAsync(Gbuf, 0, 2097152, stream);

  cast_all_k<<<dim3(7168), dim3(256), 0, stream>>>(x, y, Wqkv1, Wqkv2, W1, W2, W3, W4, xb);

  // q,k columns (0..1023)
  gemm_bt_k<u16><<<dim3(32,8,2), 256, 0, stream>>>(
      xb, 2097152, Wq1b, 1048576, nullptr, nullptr, nullptr, nullptr,
      qkv1, 8388608, 4096, 1024, 512, 2048);
  // qt columns (1536..2047)
  gemm_bt_k<u16><<<dim3(32,4,2), 256, 0, stream>>>(
      xb, 2097152, Wq1b + (size_t)1536*512, 1048576, nullptr, nullptr, nullptr, nullptr,
      qkv1 + 1536, 8388608, 4096, 512, 512, 2048);
  // V^T = Wv @ x^T  (M=512 vcols, N=4096 tokens)
  gemm_bt_k<u16><<<dim3(4,32,2), 256, 0, stream>>>(
      Wq1b + (size_t)1024*512, 1048576, xb, 2097152, nullptr, nullptr, nullptr, nullptr,
      vT1, 2097152, 512, 4096, 512, 4096);

  attn_k<<<dim3(8,32,4), 256, 0, stream>>>(qkv1, qkv2, vT1, vT2, aob);

  orthoA_k<<<dim3(32,2,4), 256, 0, stream>>>(qkv1, qkv2, Gbuf, accum);

  float* outb = (float*)d_out;
  gemm_bt_k<float><<<dim3(32,4,4), 256, 0, stream>>>(
      aob, 2097152, W1b, 262144, b1, b2, b3, b4,
      outb, 2097152, 4096, 512, 512, 512);

  orthoB_k<<<dim3(32,2), 256, 0, stream>>>(Gbuf, accum);
  lc_k<<<dim3(64), dim3(256), 0, stream>>>(outb, accum);
  fin_k<<<dim3(1), dim3(64), 0, stream>>>(accum, outb + 8388608);
}

// Round 8
// 235.113 us; speedup vs baseline: 1.8014x; 1.1494x over previous
//
#include <hip/hip_runtime.h>

typedef unsigned short u16;
typedef __attribute__((ext_vector_type(4))) unsigned short u16x4;
typedef __attribute__((ext_vector_type(8))) unsigned short u16x8;
typedef __attribute__((ext_vector_type(4))) float          f32x4;
typedef __attribute__((ext_vector_type(8))) __bf16         bf16x8;

#define MFMA16(a,b,c) __builtin_amdgcn_mfma_f32_16x16x32_bf16((a),(b),(c),0,0,0)
#define SCALE 0.125f

__device__ __forceinline__ u16 f2b(float f){
  unsigned u = __builtin_bit_cast(unsigned, f);
  u = (u + 0x7fffu + ((u >> 16) & 1u)) >> 16;
  return (u16)u;
}
__device__ __forceinline__ u16 f2b_trunc(float f){
  return (u16)(__builtin_bit_cast(unsigned, f) >> 16);
}
__device__ __forceinline__ float b2f(u16 v){
  unsigned u = ((unsigned)v) << 16;
  return __builtin_bit_cast(float, u);
}
__device__ __forceinline__ void async16(const u16* g, u16* l){
  __builtin_amdgcn_global_load_lds(
      (const __attribute__((address_space(1))) unsigned*)g,
      (__attribute__((address_space(3))) unsigned*)l, 16, 0, 0);
}
// XOR-swizzled LDS addressing: rows of 64 u16 = 8 chunks of 8.
__device__ __forceinline__ int swz(int row, int chunk, int off){
  return row*64 + (((chunk ^ row ^ (row >> 3)) & 7) << 3) + off;
}

// ---------------- fused cast f32 -> bf16 over all 8 inputs ----------------
__global__ void cast_all_k(const float* __restrict__ x, const float* __restrict__ y,
                           const float* __restrict__ wq1, const float* __restrict__ wq2,
                           const float* __restrict__ w1, const float* __restrict__ w2,
                           const float* __restrict__ w3, const float* __restrict__ w4,
                           u16* __restrict__ dst){
  int i = blockIdx.x * 256 + threadIdx.x;            // float4 index, 1,835,008 total
  const float* s; int base;
  if      (i < 524288)  { s = x;   base = 0;       }
  else if (i < 1048576) { s = y;   base = 524288;  }
  else if (i < 1310720) { s = wq1; base = 1048576; }
  else if (i < 1572864) { s = wq2; base = 1310720; }
  else if (i < 1638400) { s = w1;  base = 1572864; }
  else if (i < 1703936) { s = w2;  base = 1638400; }
  else if (i < 1769472) { s = w3;  base = 1703936; }
  else                  { s = w4;  base = 1769472; }
  float4 v = ((const float4*)s)[i - base];
  u16x4 o; o[0]=f2b(v.x); o[1]=f2b(v.y); o[2]=f2b(v.z); o[3]=f2b(v.w);
  ((u16x4*)dst)[i] = o;
}

// ---------------- mega QKV GEMM: all q/k/qt/vT tiles in one launch ----------------
// All sub-GEMMs share K=512 and row-stride-512 A,B. bf16 out.
__global__ __launch_bounds__(256, 2) void qkv_mega_k(
    const u16* __restrict__ xb, const u16* __restrict__ Wq,
    u16* __restrict__ qkv, u16* __restrict__ vT)
{
  const int i = blockIdx.x;
  const u16 *A, *B; u16* C; int ldc, m0, n0;
  if (i < 512) {                 // q,k: M=4096,N=1024
    int z = i >> 8, t = i & 255;
    m0 = (t & 31)*128; n0 = (t >> 5)*128;
    A = xb + (size_t)z*2097152; B = Wq + (size_t)z*1048576;
    C = qkv + (size_t)z*8388608; ldc = 2048;
  } else if (i < 768) {          // qt: M=4096,N=512 -> cols 1536..2047
    int z = (i-512) >> 7, t = (i-512) & 127;
    m0 = (t & 31)*128; n0 = (t >> 5)*128;
    A = xb + (size_t)z*2097152; B = Wq + (size_t)z*1048576 + (size_t)1536*512;
    C = qkv + (size_t)z*8388608 + 1536; ldc = 2048;
  } else {                       // vT = Wv @ x^T: M=512,N=4096
    int z = (i-768) >> 7, t = (i-768) & 127;
    m0 = (t & 3)*128; n0 = (t >> 2)*128;
    A = Wq + (size_t)z*1048576 + (size_t)1024*512; B = xb + (size_t)z*2097152;
    C = vT + (size_t)z*2097152; ldc = 4096;
  }

  __shared__ u16 As[128*32];
  __shared__ u16 Bs[128*32];
  const int tid  = threadIdx.x;
  const int w    = tid >> 6, lane = tid & 63;
  const int quad = lane >> 4, l16 = lane & 15;
  const int wr   = w >> 1, wc = w & 1;

  f32x4 acc[4][4] = {};
  const int rowa = lane >> 2;
  const int ko   = (lane & 3) * 8;

  for (int k0 = 0; k0 < 512; k0 += 32) {
    __syncthreads();
#pragma unroll
    for (int r = 0; r < 2; ++r) {
      int rb = (r*4 + w) * 16;
      async16(A + (size_t)(m0 + rb + rowa)*512 + k0 + ko, As + (r*4 + w)*512);
      async16(B + (size_t)(n0 + rb + rowa)*512 + k0 + ko, Bs + (r*4 + w)*512);
    }
    __syncthreads();
    bf16x8 af[4], bfr[4];
#pragma unroll
    for (int ii = 0; ii < 4; ++ii)
      af[ii] = *(const bf16x8*)&As[(wr*64 + ii*16 + l16)*32 + quad*8];
#pragma unroll
    for (int j = 0; j < 4; ++j)
      bfr[j] = *(const bf16x8*)&Bs[(wc*64 + j*16 + l16)*32 + quad*8];
#pragma unroll
    for (int ii = 0; ii < 4; ++ii)
#pragma unroll
      for (int j = 0; j < 4; ++j)
        acc[ii][j] = MFMA16(af[ii], bfr[j], acc[ii][j]);
  }
#pragma unroll
  for (int j = 0; j < 4; ++j) {
    int col = n0 + wc*64 + j*16 + l16;
#pragma unroll
    for (int ii = 0; ii < 4; ++ii)
#pragma unroll
      for (int reg = 0; reg < 4; ++reg) {
        int row = m0 + wr*64 + ii*16 + quad*4 + reg;
        C[(size_t)row*ldc + col] = f2b(acc[ii][j][reg]);
      }
  }
}

// ------- final-linear GEMM: C[M,N] = A @ B^T + bias, f32 out, z=4 batches ----
__global__ __launch_bounds__(256, 2) void gemm_fin_k(
    const u16* __restrict__ A0, size_t aStr, const u16* __restrict__ B0, size_t bStr,
    const float* __restrict__ bias0, const float* __restrict__ bias1,
    const float* __restrict__ bias2, const float* __restrict__ bias3,
    float* __restrict__ C0, size_t cStr)
{
  const int z = blockIdx.z;
  const u16* A = A0 + (size_t)z * aStr;
  const u16* Bm = B0 + (size_t)z * bStr;
  float* Cb = C0 + (size_t)z * cStr;
  const float* bias = (z==0) ? bias0 : (z==1) ? bias1 : (z==2) ? bias2 : bias3;

  __shared__ u16 As[128*32];
  __shared__ u16 Bs[128*32];
  const int tid  = threadIdx.x;
  const int w    = tid >> 6, lane = tid & 63;
  const int quad = lane >> 4, l16 = lane & 15;
  const int wr   = w >> 1, wc = w & 1;
  const int m0 = blockIdx.x * 128, n0 = blockIdx.y * 128;

  f32x4 acc[4][4] = {};
  const int rowa = lane >> 2;
  const int ko   = (lane & 3) * 8;

  for (int k0 = 0; k0 < 512; k0 += 32) {
    __syncthreads();
#pragma unroll
    for (int r = 0; r < 2; ++r) {
      int rb = (r*4 + w) * 16;
      async16(A  + (size_t)(m0 + rb + rowa)*512 + k0 + ko, As + (r*4 + w)*512);
      async16(Bm + (size_t)(n0 + rb + rowa)*512 + k0 + ko, Bs + (r*4 + w)*512);
    }
    __syncthreads();
    bf16x8 af[4], bfr[4];
#pragma unroll
    for (int ii = 0; ii < 4; ++ii)
      af[ii] = *(const bf16x8*)&As[(wr*64 + ii*16 + l16)*32 + quad*8];
#pragma unroll
    for (int j = 0; j < 4; ++j)
      bfr[j] = *(const bf16x8*)&Bs[(wc*64 + j*16 + l16)*32 + quad*8];
#pragma unroll
    for (int ii = 0; ii < 4; ++ii)
#pragma unroll
      for (int j = 0; j < 4; ++j)
        acc[ii][j] = MFMA16(af[ii], bfr[j], acc[ii][j]);
  }
#pragma unroll
  for (int j = 0; j < 4; ++j) {
    int col = n0 + wc*64 + j*16 + l16;
    float bv = bias[col];
#pragma unroll
    for (int ii = 0; ii < 4; ++ii)
#pragma unroll
      for (int reg = 0; reg < 4; ++reg) {
        int row = m0 + wr*64 + ii*16 + quad*4 + reg;
        Cb[(size_t)row*512 + col] = acc[ii][j][reg] + bv;
      }
  }
}

// ---------------- flash attention v3: paired outputs, dbuf, 1 barrier/kt ---------
// p=0: {xc=attn(qy,kx,vx), xt=attn(qtx,kx,vx)}  p=1: {yc=attn(qx,ky,vy), yt=attn(qty,ky,vy)}
// Block: 128 qrows (4 waves x 2 strips x 16). 16 K-tiles of 64 keys.
__global__ __launch_bounds__(256, 2) void attn_k(
    const u16* __restrict__ qkv1, const u16* __restrict__ qkv2,
    const u16* __restrict__ vT1, const u16* __restrict__ vT2,
    u16* __restrict__ ao)
{
  const int qt = blockIdx.x, bh = blockIdx.y, p = blockIdx.z;
  const int b = bh >> 3, h = bh & 7;
  const u16* kvsrc = p ? qkv2 : qkv1;
  const u16* vsrc  = p ? vT2 : vT1;
  const u16* qsrcA = p ? qkv1 : qkv2;  const int qoffA = h*64;           // out a=p
  const u16* qsrcB = p ? qkv2 : qkv1;  const int qoffB = 1536 + h*64;    // out a=p+2
  const int koff = 512 + h*64;
  const size_t tb = (size_t)b * 1024;

  __shared__ u16 Ks[2][4096];
  __shared__ u16 Vt[2][4096];
  __shared__ u16 Ps[4][1024];

  const int tid = threadIdx.x, w = tid >> 6, lane = tid & 63;
  const int quad = lane >> 4, l16 = lane & 15;
  const int srow = tid >> 3, sch = tid & 7;

  // Q B-frags [o][strip][half]
  bf16x8 qb[2][2][2];
#pragma unroll
  for (int s2 = 0; s2 < 2; ++s2) {
    size_t row = tb + qt*128 + w*32 + s2*16 + l16;
    const u16* qrA = qsrcA + row*2048 + qoffA;
    const u16* qrB = qsrcB + row*2048 + qoffB;
    qb[0][s2][0] = *(const bf16x8*)(qrA + quad*8);
    qb[0][s2][1] = *(const bf16x8*)(qrA + 32 + quad*8);
    qb[1][s2][0] = *(const bf16x8*)(qrB + quad*8);
    qb[1][s2][1] = *(const bf16x8*)(qrB + 32 + quad*8);
  }

  f32x4 oacc[2][2][4] = {};
  float lp[2][2] = {};
  u16* myP = Ps[w];

  u16x8 kreg[2], vreg[2];
  auto loadTile = [&](int t){
#pragma unroll
    for (int r = 0; r < 2; ++r) {
      kreg[r] = *(const u16x8*)(kvsrc + (tb + t*64 + r*32 + srow)*2048 + koff + sch*8);
      vreg[r] = *(const u16x8*)(vsrc + (size_t)(h*64 + r*32 + srow)*4096 + tb + t*64 + sch*8);
    }
  };
  auto storeTile = [&](int buf){
#pragma unroll
    for (int r = 0; r < 2; ++r) {
      *(u16x8*)&Ks[buf][swz(r*32 + srow, sch, 0)] = kreg[r];
      *(u16x8*)&Vt[buf][swz(r*32 + srow, sch, 0)] = vreg[r];
    }
  };

  loadTile(0);
  storeTile(0);
  loadTile(1);

  for (int kt = 0; kt < 16; ++kt) {
    const int cur = kt & 1;
    __syncthreads();                    // tile kt visible; prior reads of buf[cur^1] done
    if (kt < 15) storeTile(cur ^ 1);    // write tile kt+1 while computing on kt
    if (kt < 14) loadTile(kt + 2);      // global loads 2 tiles ahead

    bf16x8 ka[4][2], vb[4][2];
#pragma unroll
    for (int j = 0; j < 4; ++j) {
      ka[j][0] = *(const bf16x8*)&Ks[cur][swz(j*16 + l16, quad, 0)];
      ka[j][1] = *(const bf16x8*)&Ks[cur][swz(j*16 + l16, quad + 4, 0)];
      vb[j][0] = *(const bf16x8*)&Vt[cur][swz(j*16 + l16, quad, 0)];
      vb[j][1] = *(const bf16x8*)&Vt[cur][swz(j*16 + l16, quad + 4, 0)];
    }

#pragma unroll
    for (int o = 0; o < 2; ++o)
#pragma unroll
      for (int s2 = 0; s2 < 2; ++s2) {
        // S^T = K @ Q^T, exp in-register, pack to wave-private P
#pragma unroll
        for (int j = 0; j < 4; ++j) {
          f32x4 t = {};
          t = MFMA16(ka[j][0], qb[o][s2][0], t);
          t = MFMA16(ka[j][1], qb[o][s2][1], t);
          u16x4 pk;
#pragma unroll
          for (int reg = 0; reg < 4; ++reg) {
            float pv = __expf(t[reg] * SCALE);
            lp[o][s2] += pv;
            pk[reg] = f2b_trunc(pv);
          }
          *(u16x4*)&myP[swz(l16, j*2 + (quad >> 1), (quad & 1)*4)] = pk;
        }
        bf16x8 pa0 = *(const bf16x8*)&myP[swz(l16, quad, 0)];
        bf16x8 pa1 = *(const bf16x8*)&myP[swz(l16, quad + 4, 0)];
#pragma unroll
        for (int j = 0; j < 4; ++j) {
          oacc[o][s2][j] = MFMA16(pa0, vb[j][0], oacc[o][s2][j]);
          oacc[o][s2][j] = MFMA16(pa1, vb[j][1], oacc[o][s2][j]);
        }
      }
  }

  // epilogue
#pragma unroll
  for (int o = 0; o < 2; ++o) {
    int a = p + o*2;
    u16* aop = ao + (size_t)a*(4096*512) + (tb + qt*128)*512 + h*64;
#pragma unroll
    for (int s2 = 0; s2 < 2; ++s2) {
      float lt = lp[o][s2];
      lt += __shfl_xor(lt, 16);
      lt += __shfl_xor(lt, 32);
#pragma unroll
      for (int reg = 0; reg < 4; ++reg) {
        float lrow = __shfl(lt, quad*4 + reg);
        float linv = 1.f / lrow;
        int row = w*32 + s2*16 + quad*4 + reg;
#pragma unroll
        for (int j = 0; j < 4; ++j)
          aop[(size_t)row*512 + j*16 + l16] = f2b(oacc[o][s2][j][reg] * linv);
      }
    }
  }
}

// ---------------- ortho loss, two-phase Gram ----------------
__global__ __launch_bounds__(256, 2) void orthoA_k(
    const u16* __restrict__ qkv1, const u16* __restrict__ qkv2,
    float* __restrict__ Gbuf, float* __restrict__ accum)
{
  const int bh = blockIdx.x, which = blockIdx.y, tg = blockIdx.z;  // tg 0..7
  const u16* src = which ? qkv2 : qkv1;
  const int b = bh >> 3, h = bh & 7;
  const size_t tb = (size_t)b * 1024;

  __shared__ u16 QnT[4096], QtnT[4096];
  const int tid = threadIdx.x, w = tid >> 6, lane = tid & 63;
  const int quad = lane >> 4, l16 = lane & 15;

  f32x4 gq[4] = {}, gqt[4] = {};
  float diag = 0.f;

  for (int tt = 0; tt < 2; ++tt) {
    int t = tg*2 + tt;
    __syncthreads();
    if (tid < 128) {
      int tok = tid & 63, mat = tid >> 6;
      const u16* pp = src + (tb + t*64 + tok)*2048 + (mat ? 1536 : 0) + h*64;
      u16x8 rowv[8];
#pragma unroll
      for (int i = 0; i < 8; ++i) rowv[i] = *(const u16x8*)(pp + i*8);
      float ss = 0.f;
#pragma unroll
      for (int i = 0; i < 8; ++i)
#pragma unroll
        for (int jj = 0; jj < 8; ++jj) { float f = b2f(rowv[i][jj]); ss += f*f; }
      float inv = 1.f / fmaxf(sqrtf(ss), 1e-12f);
      u16* dst = mat ? QtnT : QnT;
#pragma unroll
      for (int i = 0; i < 8; ++i)
#pragma unroll
        for (int jj = 0; jj < 8; ++jj)
          dst[swz(i*8 + jj, tok >> 3, tok & 7)] = f2b(b2f(rowv[i][jj]) * inv);
      if (mat == 0) {
        const u16* p2 = src + (tb + t*64 + tok)*2048 + 1536 + h*64;
        float ss2 = 0.f, dot = 0.f;
#pragma unroll
        for (int i = 0; i < 8; ++i) {
          u16x8 r2 = *(const u16x8*)(p2 + i*8);
#pragma unroll
          for (int jj = 0; jj < 8; ++jj) {
            float fq = b2f(rowv[i][jj]), ft = b2f(r2[jj]);
            ss2 += ft*ft; dot += fq*ft;
          }
        }
        float inv2 = 1.f / fmaxf(sqrtf(ss2), 1e-12f);
        float dn = dot * inv * inv2;
        diag += dn * dn;
      }
    }
    __syncthreads();
    bf16x8 a0 = *(const bf16x8*)&QnT [swz(w*16 + l16, quad, 0)];
    bf16x8 a1 = *(const bf16x8*)&QnT [swz(w*16 + l16, quad + 4, 0)];
    bf16x8 t0 = *(const bf16x8*)&QtnT[swz(w*16 + l16, quad, 0)];
    bf16x8 t1 = *(const bf16x8*)&QtnT[swz(w*16 + l16, quad + 4, 0)];
#pragma unroll
    for (int j = 0; j < 4; ++j) {
      bf16x8 b0 = *(const bf16x8*)&QnT [swz(j*16 + l16, quad, 0)];
      bf16x8 b1 = *(const bf16x8*)&QnT [swz(j*16 + l16, quad + 4, 0)];
      gq[j]  = MFMA16(a0, b0, gq[j]);
      gq[j]  = MFMA16(a1, b1, gq[j]);
      bf16x8 c0 = *(const bf16x8*)&QtnT[swz(j*16 + l16, quad, 0)];
      bf16x8 c1 = *(const bf16x8*)&QtnT[swz(j*16 + l16, quad + 4, 0)];
      gqt[j] = MFMA16(t0, c0, gqt[j]);
      gqt[j] = MFMA16(t1, c1, gqt[j]);
    }
  }
  float* Gq = Gbuf + (size_t)((which*32 + bh)*2) * 4096;
  float* Gt = Gq + 4096;
#pragma unroll
  for (int j = 0; j < 4; ++j)
#pragma unroll
    for (int reg = 0; reg < 4; ++reg) {
      int row = w*16 + quad*4 + reg, col = j*16 + l16;
      atomicAdd(&Gq[row*64 + col], gq[j][reg]);
      atomicAdd(&Gt[row*64 + col], gqt[j][reg]);
    }
  if (tid < 64) atomicAdd(&accum[which], -diag);
}

// ---------------- merged reduction: lc (blocks 0..63) + orthoB (64..127) ---------
__global__ __launch_bounds__(256, 2) void red_k(
    const float* __restrict__ Gbuf, const float* __restrict__ dout,
    float* __restrict__ accum)
{
  const int tid = threadIdx.x;
  if (blockIdx.x < 64) {
    const int w = tid >> 6, lane = tid & 63;
    const int wid = blockIdx.x * 4 + w;
    float acc = 0.f;
    for (int rr = 0; rr < 16; ++rr) {
      int row = wid*16 + rr;
      const float4* xr = (const float4*)(dout + (size_t)row*512 + lane*8);
      const float4* yr = (const float4*)(dout + 2097152 + (size_t)row*512 + lane*8);
      float4 x0 = xr[0], x1 = xr[1], y0 = yr[0], y1 = yr[1];
      float dxy = x0.x*y0.x + x0.y*y0.y + x0.z*y0.z + x0.w*y0.w
                + x1.x*y1.x + x1.y*y1.y + x1.z*y1.z + x1.w*y1.w;
      float sx  = x0.x*x0.x + x0.y*x0.y + x0.z*x0.z + x0.w*x0.w
                + x1.x*x1.x + x1.y*x1.y + x1.z*x1.z + x1.w*x1.w;
      float sy  = y0.x*y0.x + y0.y*y0.y + y0.z*y0.z + y0.w*y0.w
                + y1.x*y1.x + y1.y*y1.y + y1.z*y1.z + y1.w*y1.w;
#pragma unroll
      for (int off = 32; off > 0; off >>= 1) {
        dxy += __shfl_xor(dxy, off);
        sx  += __shfl_xor(sx,  off);
        sy  += __shfl_xor(sy,  off);
      }
      if (lane == 0) {
        float cosv = dxy / (fmaxf(sqrtf(sx), 1e-12f) * fmaxf(sqrtf(sy), 1e-12f));
        acc += 1.f - cosv;
      }
    }
    if (lane == 0) atomicAdd(&accum[2], acc);
  } else {
    const int i = blockIdx.x - 64;
    const int bh = i & 31, which = i >> 5;
    const float* Gq = Gbuf + (size_t)((which*32 + bh)*2) * 4096;
    const float* Gt = Gq + 4096;
    float acc = 0.f;
    for (int idx = tid*4; idx < 4096; idx += 1024) {
      float4 g  = *(const float4*)(Gq + idx);
      float4 gt = *(const float4*)(Gt + idx);
      acc += g.x*gt.x + g.y*gt.y + g.z*gt.z + g.w*gt.w;
    }
    __shared__ float red[256];
    red[tid] = acc; __syncthreads();
    for (int s2 = 128; s2 > 0; s2 >>= 1) {
      if (tid < s2) red[tid] += red[tid + s2];
      __syncthreads();
    }
    if (tid == 0) atomicAdd(&accum[which], red[0]);
  }
}

__global__ void fin_k(const float* __restrict__ accum, float* __restrict__ outs){
  if (threadIdx.x == 0) {
    outs[0] = accum[0] * (1.f/4194304.f);
    outs[1] = accum[1] * (1.f/4194304.f);
    outs[2] = accum[2] * (1.f/4096.f);
  }
}

extern "C" void kernel_launch(void* const* d_in, const int* in_sizes, int n_in,
                              void* d_out, int out_size, void* d_ws, size_t ws_size,
                              hipStream_t stream)
{
  (void)in_sizes; (void)n_in; (void)out_size; (void)ws_size;
  const float* x     = (const float*)d_in[0];
  const float* y     = (const float*)d_in[1];
  const float* Wqkv1 = (const float*)d_in[2];
  const float* Wqkv2 = (const float*)d_in[3];
  const float* W1 = (const float*)d_in[4];
  const float* b1 = (const float*)d_in[5];
  const float* W2 = (const float*)d_in[6];
  const float* b2 = (const float*)d_in[7];
  const float* W3 = (const float*)d_in[8];
  const float* b3 = (const float*)d_in[9];
  const float* W4 = (const float*)d_in[10];
  const float* b4 = (const float*)d_in[11];

  u16* ws   = (u16*)d_ws;
  u16* xb   = ws;                                  // x,y: 2 x 2097152
  u16* Wq1b = ws + (size_t)4194304;                // 2 x 1048576
  u16* W1b  = ws + (size_t)6291456;                // 4 x 262144
  u16* qkv1 = ws + (size_t)7340032;                // 2 x 8388608
  u16* qkv2 = qkv1 + (size_t)8388608;
  u16* aob  = qkv2 + (size_t)8388608;              // 4 x 2097152
  float* accum = (float*)(aob + (size_t)8388608);
  float* Gbuf  = accum + 16;                       // 2 MB
  // V^T buffers live in d_out (consumed by attn_k before final GEMM overwrites)
  u16* vT1 = (u16*)d_out;                          // 512 x 4096 each
  u16* vT2 = vT1 + (size_t)2097152;

  hipMemsetAsync(accum, 0, 16, stream);
  hipMemsetAsync(Gbuf, 0, 2097152, stream);

  cast_all_k<<<dim3(7168), dim3(256), 0, stream>>>(x, y, Wqkv1, Wqkv2, W1, W2, W3, W4, xb);

  qkv_mega_k<<<dim3(1024), dim3(256), 0, stream>>>(xb, Wq1b, qkv1, vT1);

  attn_k<<<dim3(8,32,2), 256, 0, stream>>>(qkv1, qkv2, vT1, vT2, aob);

  orthoA_k<<<dim3(32,2,8), 256, 0, stream>>>(qkv1, qkv2, Gbuf, accum);

  float* outb = (float*)d_out;
  gemm_fin_k<<<dim3(32,4,4), 256, 0, stream>>>(
      aob, 2097152, W1b, 262144, b1, b2, b3, b4, outb, 2097152);

  red_k<<<dim3(128), 256, 0, stream>>>(Gbuf, outb, accum);
  fin_k<<<dim3(1), dim3(64), 0, stream>>>(accum, outb + 8388608);
}